// Round 13
// baseline (5671.237 us; speedup 1.0000x reference)
//
#include <hip/hip_runtime.h>
#include <hip/hip_bf16.h>

#define MROWS 4096      // B*T
#define KDIM 1024       // H
#define NVOCAB 32000    // V
#define BM 128
#define BN 128
#define NTILES (NVOCAB / BN)   // 250
#define MTILES (MROWS / BM)    // 32
#define KT 16                  // K-steps of 64
#define BETA 0.1f

typedef __attribute__((ext_vector_type(4))) int i4v;
typedef __attribute__((ext_vector_type(8))) int i8v;
typedef __attribute__((ext_vector_type(16))) float f16v;

__device__ inline void gload16(const void* g, void* l) {
  __builtin_amdgcn_global_load_lds(
      (const __attribute__((address_space(1))) void*)g,
      (__attribute__((address_space(3))) void*)l, 16, 0, 0);
}

// fp32 -> fp8 e4m3 pack into fragment-image layout (identical to r11/r12).
// Tensor rows -> tiles of 128 rows; per tile, per step (64 cols), 8192-B image;
// chunk c: blk=c>>7, r2=c&127, h=(r2>>6)&1, l=r2&63
//   row = tile*128 + blk*32 + (l&31), col = step*64 + (l>>5)*32 + h*16
__global__ void cvt_all(const float4* __restrict__ x, const float4* __restrict__ rx,
                        const float4* __restrict__ W, const float4* __restrict__ rW,
                        uint4* __restrict__ xq, uint4* __restrict__ rxq,
                        uint4* __restrict__ Wq, uint4* __restrict__ rWq) {
  const int NA = MTILES * KT * 512;    // 262144 chunks
  const int NW = NTILES * KT * 512;    // 2048000 chunks
  const int total = 2 * NA + 2 * NW;
  for (int g = blockIdx.x * 256 + threadIdx.x; g < total; g += gridDim.x * 256) {
    const float4* s; uint4* d; int j;
    if (g < NA)               { s = x;  d = xq;  j = g; }
    else if (g < 2 * NA)      { s = rx; d = rxq; j = g - NA; }
    else if (g < 2 * NA + NW) { s = W;  d = Wq;  j = g - 2 * NA; }
    else                      { s = rW; d = rWq; j = g - 2 * NA - NW; }
    const int tile = j >> 13;
    const int rem  = j & 8191;
    const int step = rem >> 9;
    const int c    = rem & 511;
    const int blk = c >> 7, r2 = c & 127;
    const int h = (r2 >> 6) & 1, l = r2 & 63;
    const int row = tile * 128 + blk * 32 + (l & 31);
    const int col = step * 64 + (l >> 5) * 32 + h * 16;
    const float4* p = s + ((size_t)row * KDIM + col) / 4;
    float4 a = p[0], b = p[1], e = p[2], f = p[3];
    unsigned w0 = __builtin_amdgcn_cvt_pk_fp8_f32(a.x, a.y, 0, false);
    w0 = __builtin_amdgcn_cvt_pk_fp8_f32(a.z, a.w, w0, true);
    unsigned w1 = __builtin_amdgcn_cvt_pk_fp8_f32(b.x, b.y, 0, false);
    w1 = __builtin_amdgcn_cvt_pk_fp8_f32(b.z, b.w, w1, true);
    unsigned w2 = __builtin_amdgcn_cvt_pk_fp8_f32(e.x, e.y, 0, false);
    w2 = __builtin_amdgcn_cvt_pk_fp8_f32(e.z, e.w, w2, true);
    unsigned w3 = __builtin_amdgcn_cvt_pk_fp8_f32(f.x, f.y, 0, false);
    w3 = __builtin_amdgcn_cvt_pk_fp8_f32(f.z, f.w, w3, true);
    d[j] = make_uint4(w0, w1, w2, w3);
  }
}

// frag loader: lane's 32 fp8 = 16B at +0 (k 0..15) and +1024 (k 16..31);
// works for LDS (A) and pre-packed global (B) alike.
__device__ inline i8v ldfrag(const unsigned char* p) {
  i4v lo = *(const i4v*)p;
  i4v hi = *(const i4v*)(p + 1024);
  return __builtin_shufflevector(lo, hi, 0, 1, 2, 3, 4, 5, 6, 7);
}

// 128x128 GEMM, MX-fp8 32x32x64 (scale=1.0). A staged in LDS (2-slot, 16 KB);
// B-fragments loaded DIRECTLY from pre-packed global (coalesced dwordx4,
// L1/L2-hot: 4 co-scheduled blocks share the ntile panel), register-prefetched
// one group ahead. LDS ~18.5 KB -> 8 blocks/CU = 32 waves = full occupancy:
// the CU matrix pipe saturates statistically across 8 barrier domains.
// grid = (8000, 2 models), block = 256 (4 waves 2x2, each 64x64 out)
__global__ __launch_bounds__(256, 8) void gemm_lse(
    const unsigned char* __restrict__ xq, const unsigned char* __restrict__ rxq,
    const unsigned char* __restrict__ Wq, const unsigned char* __restrict__ rWq,
    const int* __restrict__ y,
    float2* __restrict__ partials,  // [2][NTILES][MROWS]
    float* __restrict__ tgt)        // [2][MROWS]
{
  const int bid = blockIdx.x;       // 0..7999
  const int bz  = blockIdx.y;       // model
  // XCD banding + W-panel sharing (r12-verified: FETCH 0.26 GB)
  const int xcd   = bid & 7;
  const int idx   = bid >> 3;       // 0..999
  const int ntile = idx >> 2;       // 0..249
  const int mtile = xcd * 4 + (idx & 3);
  const int m0 = mtile * BM, n0 = ntile * BN;

  const unsigned char* Ap = (bz ? rxq : xq) + (size_t)mtile * (KT * 8192);
  const unsigned char* Bp = (bz ? rWq : Wq) + (size_t)ntile * (KT * 8192);

  const int tid = threadIdx.x;
  const int lane = tid & 63;
  const int w = tid >> 6;            // 0..3
  const int wr = w >> 1, wc = w & 1; // 2 x 2 wave grid
  const int l31 = lane & 31, hi5 = lane >> 5;

  __shared__ __align__(16) unsigned char As[2][8192];
  __shared__ int ys[BM];
  __shared__ float redM[2][BM];
  __shared__ float redS[2][BM];

  if (tid < BM) ys[tid] = y[m0 + tid];

  f16v acc[2][2];
#pragma unroll
  for (int i = 0; i < 2; ++i)
#pragma unroll
    for (int j = 0; j < 2; ++j) acc[i][j] = (f16v)(0.f);

#define STAGE(t, s)                                                     \
  {                                                                     \
    const unsigned char* a_ = Ap + (t) * 8192 + tid * 16;               \
    gload16(a_,        &As[s][tid * 16]);                               \
    gload16(a_ + 4096, &As[s][tid * 16 + 4096]);                        \
  }

  // B fragment base for this wave (frag ni at +ni*2048)
  const unsigned char* Bfrag = Bp + (wc * 2) * 2048 + lane * 16;

  // prologue: A tile 0 -> slot 0; B frags for t=0 in flight
  i8v nb0 = ldfrag(Bfrag);
  i8v nb1 = ldfrag(Bfrag + 2048);
  STAGE(0, 0);
  __syncthreads();

#pragma unroll 1
  for (int t = 0; t < KT; ++t) {
    i8v b0 = nb0, b1 = nb1;
    if (t + 1 < KT) {
      const unsigned char* bn = Bfrag + (t + 1) * 8192;
      nb0 = ldfrag(bn);
      nb1 = ldfrag(bn + 2048);
      STAGE(t + 1, (t + 1) & 1);
    }
    const unsigned char* baseA = &As[t & 1][lane * 16];
    i8v a0 = ldfrag(baseA + (wr * 2) * 2048);
    i8v a1 = ldfrag(baseA + (wr * 2 + 1) * 2048);
    acc[0][0] = __builtin_amdgcn_mfma_scale_f32_32x32x64_f8f6f4(a0, b0, acc[0][0], 0, 0, 0, 127, 0, 127);
    acc[0][1] = __builtin_amdgcn_mfma_scale_f32_32x32x64_f8f6f4(a0, b1, acc[0][1], 0, 0, 0, 127, 0, 127);
    acc[1][0] = __builtin_amdgcn_mfma_scale_f32_32x32x64_f8f6f4(a1, b0, acc[1][0], 0, 0, 0, 127, 0, 127);
    acc[1][1] = __builtin_amdgcn_mfma_scale_f32_32x32x64_f8f6f4(a1, b1, acc[1][1], 0, 0, 0, 127, 0, 127);
    __syncthreads();   // drains A(t+1) stage + slot reads; 8 blocks cover
  }
#undef STAGE

  // Epilogue: per-row (max,sumexp) over this block's 128 cols + target gather.
  // 32x32 D layout (HW-verified r3/r10/r11): col = lane&31,
  // row = (r&3)+8*(r>>2)+4*hi5
#pragma unroll
  for (int mi = 0; mi < 2; ++mi) {
#pragma unroll
    for (int r = 0; r < 16; ++r) {
      float v0 = acc[mi][0][r], v1 = acc[mi][1][r];
      float mx = fmaxf(v0, v1);
#pragma unroll
      for (int d = 1; d < 32; d <<= 1) mx = fmaxf(mx, __shfl_xor(mx, d));
      float ex = __expf(v0 - mx) + __expf(v1 - mx);
#pragma unroll
      for (int d = 1; d < 32; d <<= 1) ex += __shfl_xor(ex, d);
      int rowInBlock = wr * 64 + mi * 32 + (r & 3) + 8 * (r >> 2) + 4 * hi5;
      if (l31 == 0) { redM[wc][rowInBlock] = mx; redS[wc][rowInBlock] = ex; }
      int yv = ys[rowInBlock];
      int cl = yv - (n0 + wc * 64);
      if (cl >= 0 && cl < 64 && (cl & 31) == l31)
        tgt[(size_t)bz * MROWS + m0 + rowInBlock] = (cl >> 5) ? v1 : v0;
    }
  }
  __syncthreads();
  if (tid < BM) {
    float ma = redM[0][tid], mb = redM[1][tid];
    float sa = redS[0][tid], sb = redS[1][tid];
    float M = fmaxf(ma, mb);
    float S = sa * __expf(ma - M) + sb * __expf(mb - M);
    partials[((size_t)bz * NTILES + ntile) * MROWS + m0 + tid] = make_float2(M, S);
  }
}

// merge partials per row -> lse -> per-example mean target logp
__global__ void rowred(const float2* __restrict__ partials, const float* __restrict__ tgt,
                       const int* __restrict__ y, float* __restrict__ logps) {
  const int model = blockIdx.x >> 2;
  const int b = blockIdx.x & 3;
  const int tid = threadIdx.x;
  float sum = 0.f, cnt = 0.f;
  for (int t = tid; t < 1024; t += 256) {
    const int row = b * 1024 + t;
    float M = -INFINITY, S = 0.f;
    for (int j = 0; j < NTILES; ++j) {
      float2 v = partials[((size_t)model * NTILES + j) * MROWS + row];
      float Mn = fmaxf(M, v.x);
      S = S * __expf(M - Mn) + v.y * __expf(v.x - Mn);
      M = Mn;
    }
    int yv = y[row];
    if (yv != -100) {
      sum += tgt[(size_t)model * MROWS + row] - (M + __logf(S));
      cnt += 1.f;
    }
  }
  __shared__ float sS[4], sC[4];
#pragma unroll
  for (int d = 1; d < 64; d <<= 1) { sum += __shfl_xor(sum, d); cnt += __shfl_xor(cnt, d); }
  int w = tid >> 6;
  if ((tid & 63) == 0) { sS[w] = sum; sC[w] = cnt; }
  __syncthreads();
  if (tid == 0) {
    float s = 0.f, c = 0.f;
    for (int i = 0; i < 4; ++i) { s += sS[i]; c += sC[i]; }
    logps[blockIdx.x] = s / c;
  }
}

__global__ void finalk(const float* __restrict__ logps, const int* __restrict__ pref,
                       float* __restrict__ out) {
  if (threadIdx.x == 0 && blockIdx.x == 0) {
    float acc = 0.f;
    for (int b = 0; b < 4; ++b) {
      float lr = logps[b] - logps[4 + b];   // policy - ref
      float z = BETA * lr;
      float sig = 1.f / (1.f + __expf(-z));
      acc += (pref[b] != 0) ? (1.f - sig) : sig;
    }
    out[0] = acc * 0.25f;
  }
}

extern "C" void kernel_launch(void* const* d_in, const int* in_sizes, int n_in,
                              void* d_out, int out_size, void* d_ws, size_t ws_size,
                              hipStream_t stream) {
  const float* x    = (const float*)d_in[0];
  const float* rx   = (const float*)d_in[1];
  const int*   y    = (const int*)d_in[2];
  const int*   pref = (const int*)d_in[3];
  const float* W    = (const float*)d_in[4];
  const float* rW   = (const float*)d_in[5];
  float* out = (float*)d_out;

  char* ws = (char*)d_ws;
  const size_t SZ_X = (size_t)MROWS * KDIM;        // 4 MB (fp8 packed)
  const size_t SZ_W = (size_t)NVOCAB * KDIM;       // 32 MB (fp8 packed)
  unsigned char* xq  = (unsigned char*)(ws);
  unsigned char* rxq = (unsigned char*)(ws + SZ_X);
  unsigned char* Wq  = (unsigned char*)(ws + 2 * SZ_X);
  unsigned char* rWq = (unsigned char*)(ws + 2 * SZ_X + SZ_W);
  float2* partials = (float2*)(ws + 2 * SZ_X + 2 * SZ_W);
  float*  tgt      = (float*)(ws + 2 * SZ_X + 2 * SZ_W + (size_t)2 * NTILES * MROWS * 8);
  float*  logps    = (float*)(ws + 2 * SZ_X + 2 * SZ_W + (size_t)2 * NTILES * MROWS * 8 + 2 * MROWS * 4);

  cvt_all<<<dim3(2048), 256, 0, stream>>>((const float4*)x, (const float4*)rx,
                                          (const float4*)W, (const float4*)rW,
                                          (uint4*)xq, (uint4*)rxq, (uint4*)Wq, (uint4*)rWq);

  gemm_lse<<<dim3(8000, 2), 256, 0, stream>>>(xq, rxq, Wq, rWq, y, partials, tgt);
  rowred<<<dim3(8), 256, 0, stream>>>(partials, tgt, y, logps);
  finalk<<<dim3(1), 64, 0, stream>>>(logps, pref, out);
}

// Round 14
// 704.296 us; speedup vs baseline: 8.0523x; 8.0523x over previous
//
#include <hip/hip_runtime.h>
#include <hip/hip_bf16.h>

#define MROWS 4096      // B*T
#define KDIM 1024       // H
#define NVOCAB 32000    // V
#define MTILES (MROWS / 128)   // 32 (128-row pack tiles)
#define NTILES (NVOCAB / 128)  // 250 (128-row pack tiles)
#define NCH 500                // 64-col output chunks
#define KT 16                  // K-steps of 64
#define BETA 0.1f

typedef __attribute__((ext_vector_type(4))) int i4v;
typedef __attribute__((ext_vector_type(8))) int i8v;
typedef __attribute__((ext_vector_type(16))) float f16v;

// fp32 -> fp8 e4m3 pack into fragment-image layout (identical to r11-r13, HW-verified).
// Tensor rows -> tiles of 128 rows; per tile, per step (64 cols), 8192-B image;
// chunk c: blk=c>>7, r2=c&127, h=(r2>>6)&1, l=r2&63
//   row = tile*128 + blk*32 + (l&31), col = step*64 + (l>>5)*32 + h*16
__global__ void cvt_all(const float4* __restrict__ x, const float4* __restrict__ rx,
                        const float4* __restrict__ W, const float4* __restrict__ rW,
                        uint4* __restrict__ xq, uint4* __restrict__ rxq,
                        uint4* __restrict__ Wq, uint4* __restrict__ rWq) {
  const int NA = MTILES * KT * 512;    // 262144 chunks
  const int NW = NTILES * KT * 512;    // 2048000 chunks
  const int total = 2 * NA + 2 * NW;
  for (int g = blockIdx.x * 256 + threadIdx.x; g < total; g += gridDim.x * 256) {
    const float4* s; uint4* d; int j;
    if (g < NA)               { s = x;  d = xq;  j = g; }
    else if (g < 2 * NA)      { s = rx; d = rxq; j = g - NA; }
    else if (g < 2 * NA + NW) { s = W;  d = Wq;  j = g - 2 * NA; }
    else                      { s = rW; d = rWq; j = g - 2 * NA - NW; }
    const int tile = j >> 13;
    const int rem  = j & 8191;
    const int step = rem >> 9;
    const int c    = rem & 511;
    const int blk = c >> 7, r2 = c & 127;
    const int h = (r2 >> 6) & 1, l = r2 & 63;
    const int row = tile * 128 + blk * 32 + (l & 31);
    const int col = step * 64 + (l >> 5) * 32 + h * 16;
    const float4* p = s + ((size_t)row * KDIM + col) / 4;
    float4 a = p[0], b = p[1], e = p[2], f = p[3];
    unsigned w0 = __builtin_amdgcn_cvt_pk_fp8_f32(a.x, a.y, 0, false);
    w0 = __builtin_amdgcn_cvt_pk_fp8_f32(a.z, a.w, w0, true);
    unsigned w1 = __builtin_amdgcn_cvt_pk_fp8_f32(b.x, b.y, 0, false);
    w1 = __builtin_amdgcn_cvt_pk_fp8_f32(b.z, b.w, w1, true);
    unsigned w2 = __builtin_amdgcn_cvt_pk_fp8_f32(e.x, e.y, 0, false);
    w2 = __builtin_amdgcn_cvt_pk_fp8_f32(e.z, e.w, w2, true);
    unsigned w3 = __builtin_amdgcn_cvt_pk_fp8_f32(f.x, f.y, 0, false);
    w3 = __builtin_amdgcn_cvt_pk_fp8_f32(f.z, f.w, w3, true);
    d[j] = make_uint4(w0, w1, w2, w3);
  }
}

// frag loader from pre-packed global: lane's 32 fp8 = 16B at +0 and +1024
__device__ inline i8v ldfrag(const unsigned char* p) {
  i4v lo = *(const i4v*)p;
  i4v hi = *(const i4v*)(p + 1024);
  return __builtin_shufflevector(lo, hi, 0, 1, 2, 3, 4, 5, 6, 7);
}

// BARRIER-FREE GEMM: 1 wave per block, 64x64 output (2x2 of 32x32x64 MX-fp8),
// A and B fragments read DIRECTLY from pre-packed global (coalesced dwordx4,
// L2-resident panels) -- zero LDS, zero __syncthreads, compiler free to
// software-pipeline the whole K-loop. Epilogue reductions in-wave (shfl).
// grid = (32000, 2): xcd=bid&7, idx=bid>>3; n64=idx>>3 (8 blocks/XCD share
// one 64-row W panel), m64=xcd*8+(idx&7).
__global__ __launch_bounds__(64, 3) void gemm_lse(
    const unsigned char* __restrict__ xq, const unsigned char* __restrict__ rxq,
    const unsigned char* __restrict__ Wq, const unsigned char* __restrict__ rWq,
    const int* __restrict__ y,
    float2* __restrict__ partials,  // [2][NCH][MROWS]
    float* __restrict__ tgt)        // [2][MROWS]
{
  const int bid = blockIdx.x;       // 0..31999
  const int bz  = blockIdx.y;       // model
  const int xcd = bid & 7;
  const int idx = bid >> 3;         // 0..3999
  const int n64 = idx >> 3;         // 0..499
  const int m64 = xcd * 8 + (idx & 7);  // 0..63
  const int m0 = m64 * 64, n0 = n64 * 64;

  // packed 128-row tiles; row-block (2KB frag) index within tile
  const unsigned char* Ap = (bz ? rxq : xq) + (size_t)(m64 >> 1) * (KT * 8192)
                            + (m64 & 1) * 2 * 2048;
  const unsigned char* Bp = (bz ? rWq : Wq) + (size_t)(n64 >> 1) * (KT * 8192)
                            + (n64 & 1) * 2 * 2048;

  const int lane = threadIdx.x;
  const int l31 = lane & 31, hi5 = lane >> 5;

  const unsigned char* pa = Ap + lane * 16;
  const unsigned char* pb = Bp + lane * 16;

  f16v acc[2][2];
#pragma unroll
  for (int i = 0; i < 2; ++i)
#pragma unroll
    for (int j = 0; j < 2; ++j) acc[i][j] = (f16v)(0.f);

#pragma unroll 2
  for (int s = 0; s < KT; ++s) {
    i8v a0 = ldfrag(pa);
    i8v a1 = ldfrag(pa + 2048);
    i8v b0 = ldfrag(pb);
    i8v b1 = ldfrag(pb + 2048);
    acc[0][0] = __builtin_amdgcn_mfma_scale_f32_32x32x64_f8f6f4(a0, b0, acc[0][0], 0, 0, 0, 127, 0, 127);
    acc[0][1] = __builtin_amdgcn_mfma_scale_f32_32x32x64_f8f6f4(a0, b1, acc[0][1], 0, 0, 0, 127, 0, 127);
    acc[1][0] = __builtin_amdgcn_mfma_scale_f32_32x32x64_f8f6f4(a1, b0, acc[1][0], 0, 0, 0, 127, 0, 127);
    acc[1][1] = __builtin_amdgcn_mfma_scale_f32_32x32x64_f8f6f4(a1, b1, acc[1][1], 0, 0, 0, 127, 0, 127);
    pa += 8192;
    pb += 8192;
  }

  // Epilogue, fully in-wave. 32x32 D layout (HW-verified): col = lane&31,
  // row = (r&3)+8*(r>>2)+4*hi5 (+ mi*32). A row's 64 cols (ni=0,1) live in ONE
  // 32-lane half -> shfl_xor d<32 reduces within the half.
#pragma unroll
  for (int mi = 0; mi < 2; ++mi) {
#pragma unroll
    for (int r = 0; r < 16; ++r) {
      float v0 = acc[mi][0][r], v1 = acc[mi][1][r];
      float mx = fmaxf(v0, v1);
#pragma unroll
      for (int d = 1; d < 32; d <<= 1) mx = fmaxf(mx, __shfl_xor(mx, d));
      float ex = __expf(v0 - mx) + __expf(v1 - mx);
#pragma unroll
      for (int d = 1; d < 32; d <<= 1) ex += __shfl_xor(ex, d);
      int rowInBlock = mi * 32 + (r & 3) + 8 * (r >> 2) + 4 * hi5;
      int grow = m0 + rowInBlock;
      if (l31 == 0)
        partials[((size_t)bz * NCH + n64) * MROWS + grow] = make_float2(mx, ex);
      int yv = y[grow];
      int cl = yv - n0;
      if (cl >= 0 && cl < 64 && (cl & 31) == l31)
        tgt[(size_t)bz * MROWS + grow] = (cl >> 5) ? v1 : v0;
    }
  }
}

// merge partials per row -> lse -> per-example mean target logp
__global__ void rowred(const float2* __restrict__ partials, const float* __restrict__ tgt,
                       const int* __restrict__ y, float* __restrict__ logps) {
  const int model = blockIdx.x >> 2;
  const int b = blockIdx.x & 3;
  const int tid = threadIdx.x;
  float sum = 0.f, cnt = 0.f;
  for (int t = tid; t < 1024; t += 256) {
    const int row = b * 1024 + t;
    float M = -INFINITY, S = 0.f;
    for (int j = 0; j < NCH; ++j) {
      float2 v = partials[((size_t)model * NCH + j) * MROWS + row];
      float Mn = fmaxf(M, v.x);
      S = S * __expf(M - Mn) + v.y * __expf(v.x - Mn);
      M = Mn;
    }
    int yv = y[row];
    if (yv != -100) {
      sum += tgt[(size_t)model * MROWS + row] - (M + __logf(S));
      cnt += 1.f;
    }
  }
  __shared__ float sS[4], sC[4];
#pragma unroll
  for (int d = 1; d < 64; d <<= 1) { sum += __shfl_xor(sum, d); cnt += __shfl_xor(cnt, d); }
  int w = tid >> 6;
  if ((tid & 63) == 0) { sS[w] = sum; sC[w] = cnt; }
  __syncthreads();
  if (tid == 0) {
    float s = 0.f, c = 0.f;
    for (int i = 0; i < 4; ++i) { s += sS[i]; c += sC[i]; }
    logps[blockIdx.x] = s / c;
  }
}

__global__ void finalk(const float* __restrict__ logps, const int* __restrict__ pref,
                       float* __restrict__ out) {
  if (threadIdx.x == 0 && blockIdx.x == 0) {
    float acc = 0.f;
    for (int b = 0; b < 4; ++b) {
      float lr = logps[b] - logps[4 + b];   // policy - ref
      float z = BETA * lr;
      float sig = 1.f / (1.f + __expf(-z));
      acc += (pref[b] != 0) ? (1.f - sig) : sig;
    }
    out[0] = acc * 0.25f;
  }
}

extern "C" void kernel_launch(void* const* d_in, const int* in_sizes, int n_in,
                              void* d_out, int out_size, void* d_ws, size_t ws_size,
                              hipStream_t stream) {
  const float* x    = (const float*)d_in[0];
  const float* rx   = (const float*)d_in[1];
  const int*   y    = (const int*)d_in[2];
  const int*   pref = (const int*)d_in[3];
  const float* W    = (const float*)d_in[4];
  const float* rW   = (const float*)d_in[5];
  float* out = (float*)d_out;

  char* ws = (char*)d_ws;
  const size_t SZ_X = (size_t)MROWS * KDIM;        // 4 MB (fp8 packed)
  const size_t SZ_W = (size_t)NVOCAB * KDIM;       // 32 MB (fp8 packed)
  unsigned char* xq  = (unsigned char*)(ws);
  unsigned char* rxq = (unsigned char*)(ws + SZ_X);
  unsigned char* Wq  = (unsigned char*)(ws + 2 * SZ_X);
  unsigned char* rWq = (unsigned char*)(ws + 2 * SZ_X + SZ_W);
  float2* partials = (float2*)(ws + 2 * SZ_X + 2 * SZ_W);              // 32.8 MB
  float*  tgt      = (float*)(ws + 2 * SZ_X + 2 * SZ_W + (size_t)2 * NCH * MROWS * 8);
  float*  logps    = (float*)(ws + 2 * SZ_X + 2 * SZ_W + (size_t)2 * NCH * MROWS * 8 + 2 * MROWS * 4);

  cvt_all<<<dim3(2048), 256, 0, stream>>>((const float4*)x, (const float4*)rx,
                                          (const float4*)W, (const float4*)rW,
                                          (uint4*)xq, (uint4*)rxq, (uint4*)Wq, (uint4*)rWq);

  gemm_lse<<<dim3(32000, 2), 64, 0, stream>>>(xq, rxq, Wq, rWq, y, partials, tgt);
  rowred<<<dim3(8), 256, 0, stream>>>(partials, tgt, y, logps);
  finalk<<<dim3(1), 64, 0, stream>>>(logps, pref, out);
}